// Round 17
// baseline (294.780 us; speedup 1.0000x reference)
//
#include <hip/hip_runtime.h>
#include <hip/hip_bf16.h>
#include <math.h>

// ---------------------------------------------------------------------------
// GAT 2-layer forward. bf16 MFMA GEMMs + bf16 gather tables, fp32 softmax.
// R5: bf16 MFMA GEMMs. R8/R9: wave-per-node zero-barrier agg, 4-deep gather.
// R10-R12: alpha fused into GEMM epilogues, bf16 h1b, agg1 edge-pairs,
//          x-convert fused into GEMM0 (265us = best).
// R13/R14 (REGRESSED, reverted): XCD channel-slicing broke request structure.
// R15/R16: exact R12 + nontemporal gather loads in agg0 (as u64 — the builtin
//          rejects HIP_vector_type pointers; R15 compile error fixed).
// ---------------------------------------------------------------------------

#define NEG_SLOPE 0.2f
#define CAP0 128
#define CAP1 128

typedef __attribute__((ext_vector_type(8))) short bf16x8;
typedef __attribute__((ext_vector_type(4))) float f32x4;

static __device__ __forceinline__ unsigned f2bf_rne(float f) {
  unsigned u = __float_as_uint(f);
  return (u + 0x7fffu + ((u >> 16) & 1u)) >> 16;  // round-to-nearest-even
}
static __device__ __forceinline__ float bf2f(unsigned u16) {
  return __uint_as_float(u16 << 16);
}
static __device__ __forceinline__ void fma4u(float4& acc, float w,
                                             unsigned long long v) {
  unsigned lo = (unsigned)v, hi = (unsigned)(v >> 32);
  acc.x = fmaf(w, __uint_as_float(lo << 16), acc.x);
  acc.y = fmaf(w, __uint_as_float(lo & 0xffff0000u), acc.y);
  acc.z = fmaf(w, __uint_as_float(hi << 16), acc.z);
  acc.w = fmaf(w, __uint_as_float(hi & 0xffff0000u), acc.w);
}

// ------------------------- converts (weights only) -------------------------

__global__ void gat_cvtT_bf16(const float* __restrict__ W,
                              ushort* __restrict__ Wt, int K, int Nw) {
  int i = blockIdx.x * blockDim.x + threadIdx.x;
  if (i >= K * Nw) return;
  int n = i / K, k = i - n * K;
  Wt[i] = (ushort)f2bf_rne(W[(size_t)k * Nw + n]);
}

// ------------------------- CSR build -------------------------

__global__ void gat_count_kernel(const int* __restrict__ dst, int E, int N,
                                 int* __restrict__ counts) {
  int i = blockIdx.x * blockDim.x + threadIdx.x;
  int ET = E + N;
  if (i >= ET) return;
  int d = (i < E) ? dst[i] : (i - E);
  atomicAdd(&counts[d], 1);
}

__global__ __launch_bounds__(1024) void gat_scan_kernel(
    const int* __restrict__ counts, int* __restrict__ row_off,
    int* __restrict__ cursor, int n) {
  __shared__ int wsum[16];
  __shared__ int s_carry;
  int tid = threadIdx.x;
  int lane = tid & 63;
  int wid = tid >> 6;
  if (tid == 0) s_carry = 0;
  __syncthreads();
  const int TILE = 4096;
  for (int base = 0; base < n; base += TILE) {
    int idx = base + tid * 4;
    int4 v = {0, 0, 0, 0};
    if (idx + 3 < n) {
      v = *(const int4*)&counts[idx];
    } else {
      if (idx + 0 < n) v.x = counts[idx + 0];
      if (idx + 1 < n) v.y = counts[idx + 1];
      if (idx + 2 < n) v.z = counts[idx + 2];
      if (idx + 3 < n) v.w = counts[idx + 3];
    }
    int t0 = v.x, t1 = t0 + v.y, t2 = t1 + v.z, t3 = t2 + v.w;
    int x = t3;
    #pragma unroll
    for (int off = 1; off < 64; off <<= 1) {
      int y = __shfl_up(x, off, 64);
      if (lane >= off) x += y;
    }
    if (lane == 63) wsum[wid] = x;
    __syncthreads();
    if (tid < 16) {
      int s = wsum[tid];
      #pragma unroll
      for (int off = 1; off < 16; off <<= 1) {
        int y = __shfl_up(s, off, 16);
        if (tid >= off) s += y;
      }
      wsum[tid] = s;
    }
    __syncthreads();
    int carry = s_carry;
    int excl_wave = (wid > 0) ? wsum[wid - 1] : 0;
    int b = carry + excl_wave + (x - t3);
    if (idx + 0 < n) { row_off[idx + 0] = b;      cursor[idx + 0] = b;      }
    if (idx + 1 < n) { row_off[idx + 1] = b + t0; cursor[idx + 1] = b + t0; }
    if (idx + 2 < n) { row_off[idx + 2] = b + t1; cursor[idx + 2] = b + t1; }
    if (idx + 3 < n) { row_off[idx + 3] = b + t2; cursor[idx + 3] = b + t2; }
    __syncthreads();
    if (tid == 1023) s_carry = b + t3;  // carry + tile total
    __syncthreads();
  }
  if (threadIdx.x == 0) row_off[n] = s_carry;
}

__global__ void gat_fill_kernel(const int* __restrict__ src,
                                const int* __restrict__ dst, int E, int N,
                                int* __restrict__ cursor, int* __restrict__ col) {
  int i = blockIdx.x * blockDim.x + threadIdx.x;
  int ET = E + N;
  if (i >= ET) return;
  int s, d;
  if (i < E) { s = src[i]; d = dst[i]; }
  else       { s = d = i - E; }
  int pos = atomicAdd(&cursor[d], 1);
  col[pos] = s;
}

// ------------------------- GEMM (bf16 MFMA) + fused alpha -------------------
// C[M,N] = A[M,K] @ Bt[N,K]^T. BM=128, BK=32. THREADS/64 waves, WM x WN each.
// CVT_A: A fp32 -> bf16 during staging. ALPHA (WN==64): as/ad via 16-lane
// shuffle reduce, no atomics.

template <int THREADS, int BN, int WM, int WN, bool WRITE_BF16, bool ALPHA,
          bool CVT_A>
__global__ __launch_bounds__(THREADS) void gat_gemm_bf16(
    const float* __restrict__ Af, const ushort* __restrict__ Ab,
    const ushort* __restrict__ Bt, ushort* __restrict__ Cb, int M, int K,
    int N, const float* __restrict__ a_src, const float* __restrict__ a_dst,
    float* __restrict__ as_out, float* __restrict__ ad_out, int H) {
  constexpr int BM = 128, BK = 32;
  constexpr int MR = WM / 16, NR = WN / 16;
  constexpr int WCOLS = BN / WN;
  constexpr int RPP = THREADS / 4;  // rows staged per pass (4 thr x 8 elem)
  static_assert(BM % RPP == 0 && BN % RPP == 0, "staging");
  static_assert((BM / WM) * (BN / WN) == THREADS / 64, "wave tiling");
  __shared__ __align__(16) ushort Al[BM][40];
  __shared__ __align__(16) ushort Bl[BN][40];
  int tid = threadIdx.x;
  int lane = tid & 63, wid = tid >> 6;
  int wrow = (wid / WCOLS) * WM, wcol = (wid % WCOLS) * WN;
  int brow = blockIdx.x * BM, bcol = blockIdx.y * BN;
  int r0 = tid >> 2, seg = tid & 3;
  int kg = lane >> 4, rl = lane & 15;
  f32x4 acc[MR][NR] = {};
  for (int k0 = 0; k0 < K; k0 += BK) {
    #pragma unroll
    for (int h = 0; h < BM / RPP; ++h) {
      int row = r0 + h * RPP;
      int ar = brow + row;
      uint4 v = make_uint4(0u, 0u, 0u, 0u);
      if (ar < M) {
        if constexpr (CVT_A) {
          float4 a0 = *(const float4*)&Af[(size_t)ar * K + k0 + seg * 8];
          float4 a1 = *(const float4*)&Af[(size_t)ar * K + k0 + seg * 8 + 4];
          v.x = f2bf_rne(a0.x) | (f2bf_rne(a0.y) << 16);
          v.y = f2bf_rne(a0.z) | (f2bf_rne(a0.w) << 16);
          v.z = f2bf_rne(a1.x) | (f2bf_rne(a1.y) << 16);
          v.w = f2bf_rne(a1.z) | (f2bf_rne(a1.w) << 16);
        } else {
          v = *(const uint4*)&Ab[(size_t)ar * K + k0 + seg * 8];
        }
      }
      *(uint4*)&Al[row][seg * 8] = v;
    }
    #pragma unroll
    for (int h = 0; h < BN / RPP; ++h) {
      int row = r0 + h * RPP;
      uint4 v = *(const uint4*)&Bt[(size_t)(bcol + row) * K + k0 + seg * 8];
      *(uint4*)&Bl[row][seg * 8] = v;
    }
    __syncthreads();
    bf16x8 af[MR], bfr[NR];
    #pragma unroll
    for (int m = 0; m < MR; ++m)
      af[m] = *(const bf16x8*)&Al[wrow + m * 16 + rl][kg * 8];
    #pragma unroll
    for (int n = 0; n < NR; ++n)
      bfr[n] = *(const bf16x8*)&Bl[wcol + n * 16 + rl][kg * 8];
    #pragma unroll
    for (int m = 0; m < MR; ++m)
      #pragma unroll
      for (int n = 0; n < NR; ++n)
        acc[m][n] = __builtin_amdgcn_mfma_f32_16x16x32_bf16(
            af[m], bfr[n], acc[m][n], 0, 0, 0);
    __syncthreads();
  }
  int orow = kg * 4;
  #pragma unroll
  for (int m = 0; m < MR; ++m) {
    #pragma unroll
    for (int j = 0; j < 4; ++j) {
      int r = brow + wrow + m * 16 + orow + j;
      if (r < M) {
        #pragma unroll
        for (int n = 0; n < NR; ++n) {
          int c = bcol + wcol + n * 16 + rl;
          float v = acc[m][n][j];
          if constexpr (WRITE_BF16) Cb[(size_t)r * N + c] = (ushort)f2bf_rne(v);
        }
      }
    }
  }
  if constexpr (ALPHA) {
    static_assert(WN == 64, "alpha fusion needs one head per wave");
    int hh = (bcol + wcol) >> 6;  // head owned by this wave
    float asv[NR], adv[NR];
    #pragma unroll
    for (int n = 0; n < NR; ++n) {
      asv[n] = a_src[hh * 64 + n * 16 + rl];
      adv[n] = a_dst[hh * 64 + n * 16 + rl];
    }
    #pragma unroll
    for (int m = 0; m < MR; ++m) {
      #pragma unroll
      for (int j = 0; j < 4; ++j) {
        float ps = 0.f, pd = 0.f;
        #pragma unroll
        for (int n = 0; n < NR; ++n) {
          ps = fmaf(acc[m][n][j], asv[n], ps);
          pd = fmaf(acc[m][n][j], adv[n], pd);
        }
        #pragma unroll
        for (int off = 1; off < 16; off <<= 1) {  // reduce over rl
          ps += __shfl_xor(ps, off, 64);
          pd += __shfl_xor(pd, off, 64);
        }
        int r = brow + wrow + m * 16 + orow + j;
        if (rl == 0 && r < M) {
          as_out[(size_t)r * H + hh] = ps;
          ad_out[(size_t)r * H + hh] = pd;
        }
      }
    }
  }
}

// ------------------------- layer-0 aggregation -------------------------
// WAVE per node, zero barriers; 4-deep pipelined bf16 gather (R12 config);
// R16: gather loads nontemporal (u64 form; table oversubscribes L2 6.4x).

__global__ __launch_bounds__(256) void gat_agg0_kernel(
    const unsigned* __restrict__ h0b, const float* __restrict__ as,
    const float* __restrict__ ad, const int* __restrict__ row_off,
    const int* __restrict__ col, const float* __restrict__ bias,
    ushort* __restrict__ x1b, int N) {
  __shared__ int scol[4][CAP0];
  __shared__ float wt[4][CAP0][4];  // [wid][edge][head]
  int lane = threadIdx.x & 63;
  int wid = threadIdx.x >> 6;
  int n = blockIdx.x * 4 + wid;
  if (n >= N) return;  // whole wave exits; no barriers
  int beg = row_off[n];
  int deg = row_off[n + 1] - beg;
  int degc = deg < CAP0 ? deg : CAP0;
  for (int jj = lane; jj < degc; jj += 64) scol[wid][jj] = col[beg + jj];

  int q = lane >> 4, slot = lane & 15;
  float adv = ad[n * 4 + q];

  float m = -INFINITY;
  for (int jj = slot; jj < deg; jj += 16) {
    int s = (jj < CAP0) ? scol[wid][jj] : col[beg + jj];
    float e = as[s * 4 + q] + adv;
    e = (e > 0.f) ? e : NEG_SLOPE * e;
    if (jj < CAP0) wt[wid][jj][q] = e;
    m = fmaxf(m, e);
  }
  #pragma unroll
  for (int off = 8; off; off >>= 1) m = fmaxf(m, __shfl_xor(m, off, 64));

  float dsum = 0.f;
  for (int jj = slot; jj < deg; jj += 16) {
    float e;
    if (jj < CAP0) {
      e = wt[wid][jj][q];
    } else {
      int s = col[beg + jj];
      e = as[s * 4 + q] + adv;
      e = (e > 0.f) ? e : NEG_SLOPE * e;
    }
    float w = __expf(e - m);
    if (jj < CAP0) wt[wid][jj][q] = w;
    dsum += w;
  }
  #pragma unroll
  for (int off = 8; off; off >>= 1) dsum += __shfl_xor(dsum, off, 64);
  float inv = 1.f / (dsum + 1e-16f);

  float4 acc = make_float4(0.f, 0.f, 0.f, 0.f);
  int c2 = lane * 2;
  if (deg <= CAP0) {
    int jj = 0;
    for (; jj + 4 <= deg; jj += 4) {
      int s0 = __builtin_amdgcn_readfirstlane(scol[wid][jj + 0]);
      int s1 = __builtin_amdgcn_readfirstlane(scol[wid][jj + 1]);
      int s2 = __builtin_amdgcn_readfirstlane(scol[wid][jj + 2]);
      int s3 = __builtin_amdgcn_readfirstlane(scol[wid][jj + 3]);
      unsigned long long v0 = __builtin_nontemporal_load(
          (const unsigned long long*)(h0b + (size_t)s0 * 128 + c2));
      unsigned long long v1 = __builtin_nontemporal_load(
          (const unsigned long long*)(h0b + (size_t)s1 * 128 + c2));
      unsigned long long v2 = __builtin_nontemporal_load(
          (const unsigned long long*)(h0b + (size_t)s2 * 128 + c2));
      unsigned long long v3 = __builtin_nontemporal_load(
          (const unsigned long long*)(h0b + (size_t)s3 * 128 + c2));
      float w0 = wt[wid][jj + 0][q];
      float w1 = wt[wid][jj + 1][q];
      float w2 = wt[wid][jj + 2][q];
      float w3 = wt[wid][jj + 3][q];
      fma4u(acc, w0, v0); fma4u(acc, w1, v1);
      fma4u(acc, w2, v2); fma4u(acc, w3, v3);
    }
    for (; jj < deg; ++jj) {
      int s = __builtin_amdgcn_readfirstlane(scol[wid][jj]);
      unsigned long long v = __builtin_nontemporal_load(
          (const unsigned long long*)(h0b + (size_t)s * 128 + c2));
      fma4u(acc, wt[wid][jj][q], v);
    }
  } else {  // huge-degree fallback
    for (int jj = 0; jj < deg; ++jj) {
      int s = (jj < CAP0) ? scol[wid][jj] : col[beg + jj];
      s = __builtin_amdgcn_readfirstlane(s);
      unsigned long long v =
          *(const unsigned long long*)(h0b + (size_t)s * 128 + c2);
      float w;
      if (jj < CAP0) {
        w = wt[wid][jj][q];
      } else {
        float e = as[s * 4 + q] + adv;
        e = (e > 0.f) ? e : NEG_SLOPE * e;
        w = __expf(e - m);
      }
      fma4u(acc, w, v);
    }
  }

  int c0 = lane * 4;
  float4 bv = *(const float4*)&bias[c0];
  float o0 = acc.x * inv + bv.x;
  float o1 = acc.y * inv + bv.y;
  float o2 = acc.z * inv + bv.z;
  float o3 = acc.w * inv + bv.w;
  o0 = (o0 > 0.f) ? o0 : (__expf(o0) - 1.f);
  o1 = (o1 > 0.f) ? o1 : (__expf(o1) - 1.f);
  o2 = (o2 > 0.f) ? o2 : (__expf(o2) - 1.f);
  o3 = (o3 > 0.f) ? o3 : (__expf(o3) - 1.f);
  uint2 p;
  p.x = f2bf_rne(o0) | (f2bf_rne(o1) << 16);
  p.y = f2bf_rne(o2) | (f2bf_rne(o3) << 16);
  *(uint2*)&x1b[(size_t)n * 256 + c0] = p;
}

// ------------------------- layer-1 aggregation -------------------------
// WAVE per node, zero barriers. Edge-pair gather (R12, measured good).

__global__ __launch_bounds__(256) void gat_agg1_kernel(
    const ushort* __restrict__ h1b, const float* __restrict__ as,
    const float* __restrict__ ad, const int* __restrict__ row_off,
    const int* __restrict__ col, const float* __restrict__ bias,
    float* __restrict__ out, int N) {
  __shared__ int scol[4][CAP1];
  __shared__ float wt[4][CAP1];
  int lane = threadIdx.x & 63;
  int wid = threadIdx.x >> 6;
  int n = blockIdx.x * 4 + wid;
  if (n >= N) return;
  int beg = row_off[n];
  int deg = row_off[n + 1] - beg;
  int degc = deg < CAP1 ? deg : CAP1;
  for (int jj = lane; jj < degc; jj += 64) scol[wid][jj] = col[beg + jj];
  float adv = ad[n];

  float m = -INFINITY;
  for (int jj = lane; jj < deg; jj += 64) {
    int s = (jj < CAP1) ? scol[wid][jj] : col[beg + jj];
    float e = as[s] + adv;
    e = (e > 0.f) ? e : NEG_SLOPE * e;
    if (jj < CAP1) wt[wid][jj] = e;
    m = fmaxf(m, e);
  }
  #pragma unroll
  for (int off = 32; off; off >>= 1) m = fmaxf(m, __shfl_xor(m, off, 64));

  float dsum = 0.f;
  for (int jj = lane; jj < deg; jj += 64) {
    float e;
    if (jj < CAP1) {
      e = wt[wid][jj];
    } else {
      int s = col[beg + jj];
      e = as[s] + adv;
      e = (e > 0.f) ? e : NEG_SLOPE * e;
    }
    float w = __expf(e - m);
    if (jj < CAP1) wt[wid][jj] = w;
    dsum += w;
  }
  #pragma unroll
  for (int off = 32; off; off >>= 1) dsum += __shfl_xor(dsum, off, 64);
  float inv = 1.f / (dsum + 1e-16f);

  int half = lane >> 5, c = lane & 31;
  float ax = 0.f, ay = 0.f;
  if (deg <= CAP1) {
    int Pf = deg >> 1;  // full pairs
    int t = 0;
    for (; t + 4 <= Pf; t += 4) {
      int j0 = 2 * t + half;
      int s0 = scol[wid][j0 + 0];
      int s1 = scol[wid][j0 + 2];
      int s2 = scol[wid][j0 + 4];
      int s3 = scol[wid][j0 + 6];
      unsigned v0 = *(const unsigned*)(h1b + (size_t)s0 * 64 + c * 2);
      unsigned v1 = *(const unsigned*)(h1b + (size_t)s1 * 64 + c * 2);
      unsigned v2 = *(const unsigned*)(h1b + (size_t)s2 * 64 + c * 2);
      unsigned v3 = *(const unsigned*)(h1b + (size_t)s3 * 64 + c * 2);
      float w0 = wt[wid][j0 + 0];
      float w1 = wt[wid][j0 + 2];
      float w2 = wt[wid][j0 + 4];
      float w3 = wt[wid][j0 + 6];
      ax = fmaf(w0, bf2f(v0 & 0xffffu), ax);
      ay = fmaf(w0, bf2f(v0 >> 16), ay);
      ax = fmaf(w1, bf2f(v1 & 0xffffu), ax);
      ay = fmaf(w1, bf2f(v1 >> 16), ay);
      ax = fmaf(w2, bf2f(v2 & 0xffffu), ax);
      ay = fmaf(w2, bf2f(v2 >> 16), ay);
      ax = fmaf(w3, bf2f(v3 & 0xffffu), ax);
      ay = fmaf(w3, bf2f(v3 >> 16), ay);
    }
    for (; t < Pf; ++t) {
      int j0 = 2 * t + half;
      int s = scol[wid][j0];
      unsigned v = *(const unsigned*)(h1b + (size_t)s * 64 + c * 2);
      float w = wt[wid][j0];
      ax = fmaf(w, bf2f(v & 0xffffu), ax);
      ay = fmaf(w, bf2f(v >> 16), ay);
    }
    if (deg & 1) {  // odd tail edge: half 0 does it, half 1 gets w=0
      int jj = deg - 1;
      int s = scol[wid][jj];
      unsigned v = *(const unsigned*)(h1b + (size_t)s * 64 + c * 2);
      float w = (half == 0) ? wt[wid][jj] : 0.f;
      ax = fmaf(w, bf2f(v & 0xffffu), ax);
      ay = fmaf(w, bf2f(v >> 16), ay);
    }
  } else {  // huge-degree fallback
    int P = (deg + 1) >> 1;
    for (int t = 0; t < P; ++t) {
      int jj = 2 * t + half;
      int jc = jj < deg ? jj : (deg - 1);
      int s = (jc < CAP1) ? scol[wid][jc] : col[beg + jc];
      unsigned v = *(const unsigned*)(h1b + (size_t)s * 64 + c * 2);
      float w;
      if (jc < CAP1) {
        w = wt[wid][jc];
      } else {
        float e = as[s] + adv;
        e = (e > 0.f) ? e : NEG_SLOPE * e;
        w = __expf(e - m);
      }
      if (jj >= deg) w = 0.f;
      ax = fmaf(w, bf2f(v & 0xffffu), ax);
      ay = fmaf(w, bf2f(v >> 16), ay);
    }
  }
  ax += __shfl_xor(ax, 32, 64);
  ay += __shfl_xor(ay, 32, 64);
  if (half == 0) {
    float2 bv = *(const float2*)&bias[c * 2];
    float2 o;
    o.x = ax * inv + bv.x;
    o.y = ay * inv + bv.y;
    *(float2*)&out[(size_t)n * 64 + c * 2] = o;
  }
}

// ------------------------- launch -------------------------

extern "C" void kernel_launch(void* const* d_in, const int* in_sizes, int n_in,
                              void* d_out, int out_size, void* d_ws, size_t ws_size,
                              hipStream_t stream) {
  const float* x        = (const float*)d_in[0];
  const int*   eidx     = (const int*)d_in[1];
  const float* W0       = (const float*)d_in[2];
  const float* att_src0 = (const float*)d_in[3];
  const float* att_dst0 = (const float*)d_in[4];
  const float* b0       = (const float*)d_in[5];
  const float* W1       = (const float*)d_in[6];
  const float* att_src1 = (const float*)d_in[7];
  const float* att_dst1 = (const float*)d_in[8];
  const float* b1       = (const float*)d_in[9];
  float* out = (float*)d_out;

  const int F_IN = 256, HID = 256, H = 4, C = 64;
  const int N = in_sizes[0] / F_IN;       // 50000
  const int E = in_sizes[1] / 2;          // 800000
  const int ET = E + N;                   // with self-loops

  const int* src = eidx;
  const int* dst = eidx + E;

  // workspace layout
  char* w = (char*)d_ws;
  auto take = [&](size_t bytes) {
    char* p = w;
    w += (bytes + 255) & ~(size_t)255;
    return p;
  };
  ushort* W0t     = (ushort*)take((size_t)F_IN * HID * 2);
  ushort* W1t     = (ushort*)take((size_t)HID * C * 2);
  ushort* h0b     = (ushort*)take((size_t)N * HID * 2);
  ushort* x1b     = (ushort*)take((size_t)N * HID * 2);
  ushort* h1b     = (ushort*)take((size_t)N * C * 2);
  float*  as0     = (float*)take((size_t)N * H * 4);
  float*  ad0     = (float*)take((size_t)N * H * 4);
  float*  as1     = (float*)take((size_t)N * 4);
  float*  ad1     = (float*)take((size_t)N * 4);
  int*    row_off = (int*)take((size_t)(N + 1) * 4);
  int*    cursor  = (int*)take((size_t)N * 4);
  int*    counts  = (int*)take((size_t)N * 4);
  int*    col     = (int*)take((size_t)ET * 4);

  // --- weight converts ---
  gat_cvtT_bf16<<<(F_IN * HID + 255) / 256, 256, 0, stream>>>(W0, W0t, F_IN, HID);
  gat_cvtT_bf16<<<(HID * C + 255) / 256, 256, 0, stream>>>(W1, W1t, HID, C);

  // --- CSR build ---
  (void)hipMemsetAsync(counts, 0, (size_t)N * 4, stream);
  {
    int blocks = (ET + 255) / 256;
    gat_count_kernel<<<blocks, 256, 0, stream>>>(dst, E, N, counts);
    gat_scan_kernel<<<1, 1024, 0, stream>>>(counts, row_off, cursor, N);
    gat_fill_kernel<<<blocks, 256, 0, stream>>>(src, dst, E, N, cursor, col);
  }

  // --- layer 0: GEMM (fp32 A inline-cvt) + fused alpha ---
  {
    dim3 grid((N + 127) / 128, HID / 256);
    gat_gemm_bf16<512, 256, 64, 64, true, true, true>
        <<<grid, 512, 0, stream>>>(x, nullptr, W0t, h0b, N, F_IN, HID,
                                   att_src0, att_dst0, as0, ad0, H);
  }
  gat_agg0_kernel<<<(N + 3) / 4, 256, 0, stream>>>((const unsigned*)h0b, as0,
                                                   ad0, row_off, col, b0, x1b, N);

  // --- layer 1: GEMM (bf16 A) + fused alpha ---
  {
    dim3 grid((N + 127) / 128, C / 64);
    gat_gemm_bf16<256, 64, 32, 64, true, true, false>
        <<<grid, 256, 0, stream>>>(nullptr, x1b, W1t, h1b, N, HID, C,
                                   att_src1, att_dst1, as1, ad1, 1);
  }
  gat_agg1_kernel<<<(N + 3) / 4, 256, 0, stream>>>(h1b, as1, ad1, row_off, col,
                                                   b1, out, N);
}

// Round 18
// 268.029 us; speedup vs baseline: 1.0998x; 1.0998x over previous
//
#include <hip/hip_runtime.h>
#include <hip/hip_bf16.h>
#include <math.h>

// ---------------------------------------------------------------------------
// GAT 2-layer forward. bf16 MFMA GEMMs + bf16 gather tables, fp32 softmax.
// R5: bf16 MFMA GEMMs. R8/R9: wave-per-node zero-barrier agg, 4-deep gather.
// R10-R12: alpha fused into GEMM epilogues, bf16 h1b, agg1 edge-pairs,
//          x-convert fused into GEMM0 (265us = best).
// R13/R14 (REGRESSED, reverted): XCD channel-slicing broke request structure.
// R16 (REGRESSED, reverted): nontemporal gather loads forfeited L2 hits
//      (agg0 66->93us, FETCH unchanged) -> L2 hits are load-bearing.
// R17: exact R12 restoration (measured best: 265.1us, agg0 66.2us).
// ---------------------------------------------------------------------------

#define NEG_SLOPE 0.2f
#define CAP0 128
#define CAP1 128

typedef __attribute__((ext_vector_type(8))) short bf16x8;
typedef __attribute__((ext_vector_type(4))) float f32x4;

static __device__ __forceinline__ unsigned f2bf_rne(float f) {
  unsigned u = __float_as_uint(f);
  return (u + 0x7fffu + ((u >> 16) & 1u)) >> 16;  // round-to-nearest-even
}
static __device__ __forceinline__ float bf2f(unsigned u16) {
  return __uint_as_float(u16 << 16);
}
static __device__ __forceinline__ void fma4(float4& acc, float w, uint2 v) {
  acc.x = fmaf(w, __uint_as_float(v.x << 16), acc.x);
  acc.y = fmaf(w, __uint_as_float(v.x & 0xffff0000u), acc.y);
  acc.z = fmaf(w, __uint_as_float(v.y << 16), acc.z);
  acc.w = fmaf(w, __uint_as_float(v.y & 0xffff0000u), acc.w);
}

// ------------------------- converts (weights only) -------------------------

__global__ void gat_cvtT_bf16(const float* __restrict__ W,
                              ushort* __restrict__ Wt, int K, int Nw) {
  int i = blockIdx.x * blockDim.x + threadIdx.x;
  if (i >= K * Nw) return;
  int n = i / K, k = i - n * K;
  Wt[i] = (ushort)f2bf_rne(W[(size_t)k * Nw + n]);
}

// ------------------------- CSR build -------------------------

__global__ void gat_count_kernel(const int* __restrict__ dst, int E, int N,
                                 int* __restrict__ counts) {
  int i = blockIdx.x * blockDim.x + threadIdx.x;
  int ET = E + N;
  if (i >= ET) return;
  int d = (i < E) ? dst[i] : (i - E);
  atomicAdd(&counts[d], 1);
}

__global__ __launch_bounds__(1024) void gat_scan_kernel(
    const int* __restrict__ counts, int* __restrict__ row_off,
    int* __restrict__ cursor, int n) {
  __shared__ int wsum[16];
  __shared__ int s_carry;
  int tid = threadIdx.x;
  int lane = tid & 63;
  int wid = tid >> 6;
  if (tid == 0) s_carry = 0;
  __syncthreads();
  const int TILE = 4096;
  for (int base = 0; base < n; base += TILE) {
    int idx = base + tid * 4;
    int4 v = {0, 0, 0, 0};
    if (idx + 3 < n) {
      v = *(const int4*)&counts[idx];
    } else {
      if (idx + 0 < n) v.x = counts[idx + 0];
      if (idx + 1 < n) v.y = counts[idx + 1];
      if (idx + 2 < n) v.z = counts[idx + 2];
      if (idx + 3 < n) v.w = counts[idx + 3];
    }
    int t0 = v.x, t1 = t0 + v.y, t2 = t1 + v.z, t3 = t2 + v.w;
    int x = t3;
    #pragma unroll
    for (int off = 1; off < 64; off <<= 1) {
      int y = __shfl_up(x, off, 64);
      if (lane >= off) x += y;
    }
    if (lane == 63) wsum[wid] = x;
    __syncthreads();
    if (tid < 16) {
      int s = wsum[tid];
      #pragma unroll
      for (int off = 1; off < 16; off <<= 1) {
        int y = __shfl_up(s, off, 16);
        if (tid >= off) s += y;
      }
      wsum[tid] = s;
    }
    __syncthreads();
    int carry = s_carry;
    int excl_wave = (wid > 0) ? wsum[wid - 1] : 0;
    int b = carry + excl_wave + (x - t3);
    if (idx + 0 < n) { row_off[idx + 0] = b;      cursor[idx + 0] = b;      }
    if (idx + 1 < n) { row_off[idx + 1] = b + t0; cursor[idx + 1] = b + t0; }
    if (idx + 2 < n) { row_off[idx + 2] = b + t1; cursor[idx + 2] = b + t1; }
    if (idx + 3 < n) { row_off[idx + 3] = b + t2; cursor[idx + 3] = b + t2; }
    __syncthreads();
    if (tid == 1023) s_carry = b + t3;  // carry + tile total
    __syncthreads();
  }
  if (threadIdx.x == 0) row_off[n] = s_carry;
}

__global__ void gat_fill_kernel(const int* __restrict__ src,
                                const int* __restrict__ dst, int E, int N,
                                int* __restrict__ cursor, int* __restrict__ col) {
  int i = blockIdx.x * blockDim.x + threadIdx.x;
  int ET = E + N;
  if (i >= ET) return;
  int s, d;
  if (i < E) { s = src[i]; d = dst[i]; }
  else       { s = d = i - E; }
  int pos = atomicAdd(&cursor[d], 1);
  col[pos] = s;
}

// ------------------------- GEMM (bf16 MFMA) + fused alpha -------------------
// C[M,N] = A[M,K] @ Bt[N,K]^T. BM=128, BK=32. THREADS/64 waves, WM x WN each.
// CVT_A: A fp32 -> bf16 during staging. ALPHA (WN==64): as/ad via 16-lane
// shuffle reduce, no atomics.

template <int THREADS, int BN, int WM, int WN, bool WRITE_BF16, bool ALPHA,
          bool CVT_A>
__global__ __launch_bounds__(THREADS) void gat_gemm_bf16(
    const float* __restrict__ Af, const ushort* __restrict__ Ab,
    const ushort* __restrict__ Bt, ushort* __restrict__ Cb, int M, int K,
    int N, const float* __restrict__ a_src, const float* __restrict__ a_dst,
    float* __restrict__ as_out, float* __restrict__ ad_out, int H) {
  constexpr int BM = 128, BK = 32;
  constexpr int MR = WM / 16, NR = WN / 16;
  constexpr int WCOLS = BN / WN;
  constexpr int RPP = THREADS / 4;  // rows staged per pass (4 thr x 8 elem)
  static_assert(BM % RPP == 0 && BN % RPP == 0, "staging");
  static_assert((BM / WM) * (BN / WN) == THREADS / 64, "wave tiling");
  __shared__ __align__(16) ushort Al[BM][40];
  __shared__ __align__(16) ushort Bl[BN][40];
  int tid = threadIdx.x;
  int lane = tid & 63, wid = tid >> 6;
  int wrow = (wid / WCOLS) * WM, wcol = (wid % WCOLS) * WN;
  int brow = blockIdx.x * BM, bcol = blockIdx.y * BN;
  int r0 = tid >> 2, seg = tid & 3;
  int kg = lane >> 4, rl = lane & 15;
  f32x4 acc[MR][NR] = {};
  for (int k0 = 0; k0 < K; k0 += BK) {
    #pragma unroll
    for (int h = 0; h < BM / RPP; ++h) {
      int row = r0 + h * RPP;
      int ar = brow + row;
      uint4 v = make_uint4(0u, 0u, 0u, 0u);
      if (ar < M) {
        if constexpr (CVT_A) {
          float4 a0 = *(const float4*)&Af[(size_t)ar * K + k0 + seg * 8];
          float4 a1 = *(const float4*)&Af[(size_t)ar * K + k0 + seg * 8 + 4];
          v.x = f2bf_rne(a0.x) | (f2bf_rne(a0.y) << 16);
          v.y = f2bf_rne(a0.z) | (f2bf_rne(a0.w) << 16);
          v.z = f2bf_rne(a1.x) | (f2bf_rne(a1.y) << 16);
          v.w = f2bf_rne(a1.z) | (f2bf_rne(a1.w) << 16);
        } else {
          v = *(const uint4*)&Ab[(size_t)ar * K + k0 + seg * 8];
        }
      }
      *(uint4*)&Al[row][seg * 8] = v;
    }
    #pragma unroll
    for (int h = 0; h < BN / RPP; ++h) {
      int row = r0 + h * RPP;
      uint4 v = *(const uint4*)&Bt[(size_t)(bcol + row) * K + k0 + seg * 8];
      *(uint4*)&Bl[row][seg * 8] = v;
    }
    __syncthreads();
    bf16x8 af[MR], bfr[NR];
    #pragma unroll
    for (int m = 0; m < MR; ++m)
      af[m] = *(const bf16x8*)&Al[wrow + m * 16 + rl][kg * 8];
    #pragma unroll
    for (int n = 0; n < NR; ++n)
      bfr[n] = *(const bf16x8*)&Bl[wcol + n * 16 + rl][kg * 8];
    #pragma unroll
    for (int m = 0; m < MR; ++m)
      #pragma unroll
      for (int n = 0; n < NR; ++n)
        acc[m][n] = __builtin_amdgcn_mfma_f32_16x16x32_bf16(
            af[m], bfr[n], acc[m][n], 0, 0, 0);
    __syncthreads();
  }
  int orow = kg * 4;
  #pragma unroll
  for (int m = 0; m < MR; ++m) {
    #pragma unroll
    for (int j = 0; j < 4; ++j) {
      int r = brow + wrow + m * 16 + orow + j;
      if (r < M) {
        #pragma unroll
        for (int n = 0; n < NR; ++n) {
          int c = bcol + wcol + n * 16 + rl;
          float v = acc[m][n][j];
          if constexpr (WRITE_BF16) Cb[(size_t)r * N + c] = (ushort)f2bf_rne(v);
        }
      }
    }
  }
  if constexpr (ALPHA) {
    static_assert(WN == 64, "alpha fusion needs one head per wave");
    int hh = (bcol + wcol) >> 6;  // head owned by this wave
    float asv[NR], adv[NR];
    #pragma unroll
    for (int n = 0; n < NR; ++n) {
      asv[n] = a_src[hh * 64 + n * 16 + rl];
      adv[n] = a_dst[hh * 64 + n * 16 + rl];
    }
    #pragma unroll
    for (int m = 0; m < MR; ++m) {
      #pragma unroll
      for (int j = 0; j < 4; ++j) {
        float ps = 0.f, pd = 0.f;
        #pragma unroll
        for (int n = 0; n < NR; ++n) {
          ps = fmaf(acc[m][n][j], asv[n], ps);
          pd = fmaf(acc[m][n][j], adv[n], pd);
        }
        #pragma unroll
        for (int off = 1; off < 16; off <<= 1) {  // reduce over rl
          ps += __shfl_xor(ps, off, 64);
          pd += __shfl_xor(pd, off, 64);
        }
        int r = brow + wrow + m * 16 + orow + j;
        if (rl == 0 && r < M) {
          as_out[(size_t)r * H + hh] = ps;
          ad_out[(size_t)r * H + hh] = pd;
        }
      }
    }
  }
}

// ------------------------- layer-0 aggregation -------------------------
// WAVE per node, zero barriers; 4-deep pipelined bf16 gather (R12 config).

__global__ __launch_bounds__(256) void gat_agg0_kernel(
    const unsigned* __restrict__ h0b, const float* __restrict__ as,
    const float* __restrict__ ad, const int* __restrict__ row_off,
    const int* __restrict__ col, const float* __restrict__ bias,
    ushort* __restrict__ x1b, int N) {
  __shared__ int scol[4][CAP0];
  __shared__ float wt[4][CAP0][4];  // [wid][edge][head]
  int lane = threadIdx.x & 63;
  int wid = threadIdx.x >> 6;
  int n = blockIdx.x * 4 + wid;
  if (n >= N) return;  // whole wave exits; no barriers
  int beg = row_off[n];
  int deg = row_off[n + 1] - beg;
  int degc = deg < CAP0 ? deg : CAP0;
  for (int jj = lane; jj < degc; jj += 64) scol[wid][jj] = col[beg + jj];

  int q = lane >> 4, slot = lane & 15;
  float adv = ad[n * 4 + q];

  float m = -INFINITY;
  for (int jj = slot; jj < deg; jj += 16) {
    int s = (jj < CAP0) ? scol[wid][jj] : col[beg + jj];
    float e = as[s * 4 + q] + adv;
    e = (e > 0.f) ? e : NEG_SLOPE * e;
    if (jj < CAP0) wt[wid][jj][q] = e;
    m = fmaxf(m, e);
  }
  #pragma unroll
  for (int off = 8; off; off >>= 1) m = fmaxf(m, __shfl_xor(m, off, 64));

  float dsum = 0.f;
  for (int jj = slot; jj < deg; jj += 16) {
    float e;
    if (jj < CAP0) {
      e = wt[wid][jj][q];
    } else {
      int s = col[beg + jj];
      e = as[s * 4 + q] + adv;
      e = (e > 0.f) ? e : NEG_SLOPE * e;
    }
    float w = __expf(e - m);
    if (jj < CAP0) wt[wid][jj][q] = w;
    dsum += w;
  }
  #pragma unroll
  for (int off = 8; off; off >>= 1) dsum += __shfl_xor(dsum, off, 64);
  float inv = 1.f / (dsum + 1e-16f);

  float4 acc = make_float4(0.f, 0.f, 0.f, 0.f);
  int c2 = lane * 2;
  if (deg <= CAP0) {
    int jj = 0;
    for (; jj + 4 <= deg; jj += 4) {
      int s0 = __builtin_amdgcn_readfirstlane(scol[wid][jj + 0]);
      int s1 = __builtin_amdgcn_readfirstlane(scol[wid][jj + 1]);
      int s2 = __builtin_amdgcn_readfirstlane(scol[wid][jj + 2]);
      int s3 = __builtin_amdgcn_readfirstlane(scol[wid][jj + 3]);
      uint2 v0 = *(const uint2*)(h0b + (size_t)s0 * 128 + c2);
      uint2 v1 = *(const uint2*)(h0b + (size_t)s1 * 128 + c2);
      uint2 v2 = *(const uint2*)(h0b + (size_t)s2 * 128 + c2);
      uint2 v3 = *(const uint2*)(h0b + (size_t)s3 * 128 + c2);
      float w0 = wt[wid][jj + 0][q];
      float w1 = wt[wid][jj + 1][q];
      float w2 = wt[wid][jj + 2][q];
      float w3 = wt[wid][jj + 3][q];
      fma4(acc, w0, v0); fma4(acc, w1, v1);
      fma4(acc, w2, v2); fma4(acc, w3, v3);
    }
    for (; jj < deg; ++jj) {
      int s = __builtin_amdgcn_readfirstlane(scol[wid][jj]);
      uint2 v = *(const uint2*)(h0b + (size_t)s * 128 + c2);
      fma4(acc, wt[wid][jj][q], v);
    }
  } else {  // huge-degree fallback
    for (int jj = 0; jj < deg; ++jj) {
      int s = (jj < CAP0) ? scol[wid][jj] : col[beg + jj];
      s = __builtin_amdgcn_readfirstlane(s);
      uint2 v = *(const uint2*)(h0b + (size_t)s * 128 + c2);
      float w;
      if (jj < CAP0) {
        w = wt[wid][jj][q];
      } else {
        float e = as[s * 4 + q] + adv;
        e = (e > 0.f) ? e : NEG_SLOPE * e;
        w = __expf(e - m);
      }
      fma4(acc, w, v);
    }
  }

  int c0 = lane * 4;
  float4 bv = *(const float4*)&bias[c0];
  float o0 = acc.x * inv + bv.x;
  float o1 = acc.y * inv + bv.y;
  float o2 = acc.z * inv + bv.z;
  float o3 = acc.w * inv + bv.w;
  o0 = (o0 > 0.f) ? o0 : (__expf(o0) - 1.f);
  o1 = (o1 > 0.f) ? o1 : (__expf(o1) - 1.f);
  o2 = (o2 > 0.f) ? o2 : (__expf(o2) - 1.f);
  o3 = (o3 > 0.f) ? o3 : (__expf(o3) - 1.f);
  uint2 p;
  p.x = f2bf_rne(o0) | (f2bf_rne(o1) << 16);
  p.y = f2bf_rne(o2) | (f2bf_rne(o3) << 16);
  *(uint2*)&x1b[(size_t)n * 256 + c0] = p;
}

// ------------------------- layer-1 aggregation -------------------------
// WAVE per node, zero barriers. Edge-pair gather (R12, measured good).

__global__ __launch_bounds__(256) void gat_agg1_kernel(
    const ushort* __restrict__ h1b, const float* __restrict__ as,
    const float* __restrict__ ad, const int* __restrict__ row_off,
    const int* __restrict__ col, const float* __restrict__ bias,
    float* __restrict__ out, int N) {
  __shared__ int scol[4][CAP1];
  __shared__ float wt[4][CAP1];
  int lane = threadIdx.x & 63;
  int wid = threadIdx.x >> 6;
  int n = blockIdx.x * 4 + wid;
  if (n >= N) return;
  int beg = row_off[n];
  int deg = row_off[n + 1] - beg;
  int degc = deg < CAP1 ? deg : CAP1;
  for (int jj = lane; jj < degc; jj += 64) scol[wid][jj] = col[beg + jj];
  float adv = ad[n];

  float m = -INFINITY;
  for (int jj = lane; jj < deg; jj += 64) {
    int s = (jj < CAP1) ? scol[wid][jj] : col[beg + jj];
    float e = as[s] + adv;
    e = (e > 0.f) ? e : NEG_SLOPE * e;
    if (jj < CAP1) wt[wid][jj] = e;
    m = fmaxf(m, e);
  }
  #pragma unroll
  for (int off = 32; off; off >>= 1) m = fmaxf(m, __shfl_xor(m, off, 64));

  float dsum = 0.f;
  for (int jj = lane; jj < deg; jj += 64) {
    float e;
    if (jj < CAP1) {
      e = wt[wid][jj];
    } else {
      int s = col[beg + jj];
      e = as[s] + adv;
      e = (e > 0.f) ? e : NEG_SLOPE * e;
    }
    float w = __expf(e - m);
    if (jj < CAP1) wt[wid][jj] = w;
    dsum += w;
  }
  #pragma unroll
  for (int off = 32; off; off >>= 1) dsum += __shfl_xor(dsum, off, 64);
  float inv = 1.f / (dsum + 1e-16f);

  int half = lane >> 5, c = lane & 31;
  float ax = 0.f, ay = 0.f;
  if (deg <= CAP1) {
    int Pf = deg >> 1;  // full pairs
    int t = 0;
    for (; t + 4 <= Pf; t += 4) {
      int j0 = 2 * t + half;
      int s0 = scol[wid][j0 + 0];
      int s1 = scol[wid][j0 + 2];
      int s2 = scol[wid][j0 + 4];
      int s3 = scol[wid][j0 + 6];
      unsigned v0 = *(const unsigned*)(h1b + (size_t)s0 * 64 + c * 2);
      unsigned v1 = *(const unsigned*)(h1b + (size_t)s1 * 64 + c * 2);
      unsigned v2 = *(const unsigned*)(h1b + (size_t)s2 * 64 + c * 2);
      unsigned v3 = *(const unsigned*)(h1b + (size_t)s3 * 64 + c * 2);
      float w0 = wt[wid][j0 + 0];
      float w1 = wt[wid][j0 + 2];
      float w2 = wt[wid][j0 + 4];
      float w3 = wt[wid][j0 + 6];
      ax = fmaf(w0, bf2f(v0 & 0xffffu), ax);
      ay = fmaf(w0, bf2f(v0 >> 16), ay);
      ax = fmaf(w1, bf2f(v1 & 0xffffu), ax);
      ay = fmaf(w1, bf2f(v1 >> 16), ay);
      ax = fmaf(w2, bf2f(v2 & 0xffffu), ax);
      ay = fmaf(w2, bf2f(v2 >> 16), ay);
      ax = fmaf(w3, bf2f(v3 & 0xffffu), ax);
      ay = fmaf(w3, bf2f(v3 >> 16), ay);
    }
    for (; t < Pf; ++t) {
      int j0 = 2 * t + half;
      int s = scol[wid][j0];
      unsigned v = *(const unsigned*)(h1b + (size_t)s * 64 + c * 2);
      float w = wt[wid][j0];
      ax = fmaf(w, bf2f(v & 0xffffu), ax);
      ay = fmaf(w, bf2f(v >> 16), ay);
    }
    if (deg & 1) {  // odd tail edge: half 0 does it, half 1 gets w=0
      int jj = deg - 1;
      int s = scol[wid][jj];
      unsigned v = *(const unsigned*)(h1b + (size_t)s * 64 + c * 2);
      float w = (half == 0) ? wt[wid][jj] : 0.f;
      ax = fmaf(w, bf2f(v & 0xffffu), ax);
      ay = fmaf(w, bf2f(v >> 16), ay);
    }
  } else {  // huge-degree fallback
    int P = (deg + 1) >> 1;
    for (int t = 0; t < P; ++t) {
      int jj = 2 * t + half;
      int jc = jj < deg ? jj : (deg - 1);
      int s = (jc < CAP1) ? scol[wid][jc] : col[beg + jc];
      unsigned v = *(const unsigned*)(h1b + (size_t)s * 64 + c * 2);
      float w;
      if (jc < CAP1) {
        w = wt[wid][jc];
      } else {
        float e = as[s] + adv;
        e = (e > 0.f) ? e : NEG_SLOPE * e;
        w = __expf(e - m);
      }
      if (jj >= deg) w = 0.f;
      ax = fmaf(w, bf2f(v & 0xffffu), ax);
      ay = fmaf(w, bf2f(v >> 16), ay);
    }
  }
  ax += __shfl_xor(ax, 32, 64);
  ay += __shfl_xor(ay, 32, 64);
  if (half == 0) {
    float2 bv = *(const float2*)&bias[c * 2];
    float2 o;
    o.x = ax * inv + bv.x;
    o.y = ay * inv + bv.y;
    *(float2*)&out[(size_t)n * 64 + c * 2] = o;
  }
}

// ------------------------- launch -------------------------

extern "C" void kernel_launch(void* const* d_in, const int* in_sizes, int n_in,
                              void* d_out, int out_size, void* d_ws, size_t ws_size,
                              hipStream_t stream) {
  const float* x        = (const float*)d_in[0];
  const int*   eidx     = (const int*)d_in[1];
  const float* W0       = (const float*)d_in[2];
  const float* att_src0 = (const float*)d_in[3];
  const float* att_dst0 = (const float*)d_in[4];
  const float* b0       = (const float*)d_in[5];
  const float* W1       = (const float*)d_in[6];
  const float* att_src1 = (const float*)d_in[7];
  const float* att_dst1 = (const float*)d_in[8];
  const float* b1       = (const float*)d_in[9];
  float* out = (float*)d_out;

  const int F_IN = 256, HID = 256, H = 4, C = 64;
  const int N = in_sizes[0] / F_IN;       // 50000
  const int E = in_sizes[1] / 2;          // 800000
  const int ET = E + N;                   // with self-loops

  const int* src = eidx;
  const int* dst = eidx + E;

  // workspace layout
  char* w = (char*)d_ws;
  auto take = [&](size_t bytes) {
    char* p = w;
    w += (bytes + 255) & ~(size_t)255;
    return p;
  };
  ushort* W0t     = (ushort*)take((size_t)F_IN * HID * 2);
  ushort* W1t     = (ushort*)take((size_t)HID * C * 2);
  ushort* h0b     = (ushort*)take((size_t)N * HID * 2);
  ushort* x1b     = (ushort*)take((size_t)N * HID * 2);
  ushort* h1b     = (ushort*)take((size_t)N * C * 2);
  float*  as0     = (float*)take((size_t)N * H * 4);
  float*  ad0     = (float*)take((size_t)N * H * 4);
  float*  as1     = (float*)take((size_t)N * 4);
  float*  ad1     = (float*)take((size_t)N * 4);
  int*    row_off = (int*)take((size_t)(N + 1) * 4);
  int*    cursor  = (int*)take((size_t)N * 4);
  int*    counts  = (int*)take((size_t)N * 4);
  int*    col     = (int*)take((size_t)ET * 4);

  // --- weight converts ---
  gat_cvtT_bf16<<<(F_IN * HID + 255) / 256, 256, 0, stream>>>(W0, W0t, F_IN, HID);
  gat_cvtT_bf16<<<(HID * C + 255) / 256, 256, 0, stream>>>(W1, W1t, HID, C);

  // --- CSR build ---
  (void)hipMemsetAsync(counts, 0, (size_t)N * 4, stream);
  {
    int blocks = (ET + 255) / 256;
    gat_count_kernel<<<blocks, 256, 0, stream>>>(dst, E, N, counts);
    gat_scan_kernel<<<1, 1024, 0, stream>>>(counts, row_off, cursor, N);
    gat_fill_kernel<<<blocks, 256, 0, stream>>>(src, dst, E, N, cursor, col);
  }

  // --- layer 0: GEMM (fp32 A inline-cvt) + fused alpha ---
  {
    dim3 grid((N + 127) / 128, HID / 256);
    gat_gemm_bf16<512, 256, 64, 64, true, true, true>
        <<<grid, 512, 0, stream>>>(x, nullptr, W0t, h0b, N, F_IN, HID,
                                   att_src0, att_dst0, as0, ad0, H);
  }
  gat_agg0_kernel<<<(N + 3) / 4, 256, 0, stream>>>((const unsigned*)h0b, as0,
                                                   ad0, row_off, col, b0, x1b, N);

  // --- layer 1: GEMM (bf16 A) + fused alpha ---
  {
    dim3 grid((N + 127) / 128, C / 64);
    gat_gemm_bf16<256, 64, 32, 64, true, true, false>
        <<<grid, 256, 0, stream>>>(nullptr, x1b, W1t, h1b, N, HID, C,
                                   att_src1, att_dst1, as1, ad1, 1);
  }
  gat_agg1_kernel<<<(N + 3) / 4, 256, 0, stream>>>(h1b, as1, ad1, row_off, col,
                                                   b1, out, N);
}